// Round 1
// baseline (22130.605 us; speedup 1.0000x reference)
//
#include <hip/hip_runtime.h>

#define T_LEN 512
#define B_SZ  64
#define I_SZ  512
#define H_SZ  512

using half8   = __attribute__((ext_vector_type(8))) _Float16;
using float4v = __attribute__((ext_vector_type(4))) float;

// ---------------------------------------------------------------------------
// Kernel 1: input projection GEMM (f16 MFMA, fp32 accumulate)
//   xp[dir][t][b][h] = sum_i x[b][t][i] * Wx[dir][h][i] + bx[dir][h]  (f16)
// Grid: 8192 blocks = 512 t-tiles x 8 h-tiles x 2 dirs, 256 threads.
// Tile: M=64 (all b of one t), N=64 (h), K=512 in chunks of 64 via LDS.
// ---------------------------------------------------------------------------
__global__ __launch_bounds__(256) void xproj_kernel(
    const float* __restrict__ x,
    const float* __restrict__ Wf, const float* __restrict__ bf,
    const float* __restrict__ Wb, const float* __restrict__ bb,
    _Float16* __restrict__ xp)
{
    __shared__ _Float16 Ash[64][72];   // +8 f16 pad per row
    __shared__ _Float16 Bsh[64][72];

    const int bid = blockIdx.x;
    const int dir = bid & 1;
    const int nt  = (bid >> 1) & 7;
    const int t   = bid >> 4;                 // 0..511
    const float* __restrict__ W    = dir ? Wb : Wf;
    const float* __restrict__ bias = dir ? bb : bf;
    const int n0 = nt * 64;

    const int tid  = threadIdx.x;
    const int row  = tid >> 2;                // 0..63
    const int part = tid & 3;                 // 16-float chunk within K-64
    const int wv   = tid >> 6;                // wave 0..3 -> m-subtile
    const int lane = tid & 63;
    const int lm   = lane & 15;
    const int lq   = lane >> 4;

    float4v acc[4] = {{0,0,0,0},{0,0,0,0},{0,0,0,0},{0,0,0,0}};

    const float* ap = x + ((size_t)row * T_LEN + t) * I_SZ + part * 16;
    const float* bp = W + ((size_t)(n0 + row)) * I_SZ + part * 16;

    for (int k0 = 0; k0 < I_SZ; k0 += 64) {
        float areg[16], breg[16];
        #pragma unroll
        for (int i = 0; i < 16; i++) { areg[i] = ap[k0 + i]; breg[i] = bp[k0 + i]; }
        __syncthreads();                       // protect previous-iter LDS reads
        #pragma unroll
        for (int i = 0; i < 16; i++) {
            Ash[row][part*16 + i] = (_Float16)areg[i];
            Bsh[row][part*16 + i] = (_Float16)breg[i];
        }
        __syncthreads();
        #pragma unroll
        for (int ks = 0; ks < 2; ks++) {
            // A-operand layout: A[m=lane&15][k=(lane>>4)*8+j]
            half8 afr = *(const half8*)&Ash[16*wv + lm][ks*32 + lq*8];
            #pragma unroll
            for (int ns = 0; ns < 4; ns++) {
                half8 bfr = *(const half8*)&Bsh[ns*16 + lm][ks*32 + lq*8];
                acc[ns] = __builtin_amdgcn_mfma_f32_16x16x32_f16(afr, bfr, acc[ns], 0, 0, 0);
            }
        }
    }

    // C/D layout: col n = lane&15, row m = (lane>>4)*4 + reg
    #pragma unroll
    for (int ns = 0; ns < 4; ns++) {
        const int n = n0 + ns*16 + lm;
        const float bv = bias[n];
        #pragma unroll
        for (int j = 0; j < 4; j++) {
            const int b = 16*wv + lq*4 + j;
            xp[(((size_t)dir*T_LEN + t)*B_SZ + b)*H_SZ + n] = (_Float16)(acc[ns][j] + bv);
        }
    }
}

// ---------------------------------------------------------------------------
// Kernel 2: bidirectional recurrence.
// 256 blocks x 256 threads. cluster = blk & 31 (8 WGs per cluster share an XCD
// under round-robin dispatch), w8 = blk >> 5 selects the 64-row Wh slice.
// Each cluster owns 4 batch chains of one direction. Wh slice lives in VGPRs
// as f16 MFMA B-fragments for all 512 steps. h ping-pongs through a global
// 2-buffer (per-cluster) with a device-scope arrival-counter barrier per step.
// M=16 MFMA tile: chains 0..3 real, rows 4..15 are zero padding.
// ---------------------------------------------------------------------------
__global__ __launch_bounds__(256) void rnn_kernel(
    const _Float16* __restrict__ xp,     // [2][T][B][H] f16
    const float* __restrict__ Whf, const float* __restrict__ Whb,  // [H][H]
    const float* __restrict__ h0f, const float* __restrict__ h0b,  // [B][H]
    float* __restrict__ out,             // y[B][T][2H] ++ hTf[B][H] ++ hTb[B][H]
    _Float16* __restrict__ hglob,        // [32][2][16][512] f16
    int* __restrict__ bar)               // [32] counters, stride 32 ints
{
    const int blk     = blockIdx.x;
    const int cluster = blk & 31;
    const int w8      = blk >> 5;        // 0..7: row-slice
    const int dir     = cluster >> 4;
    const int b0      = (cluster & 15) * 4;
    const int tid     = threadIdx.x;
    const int wv      = tid >> 6;
    const int lane    = tid & 63;
    const int lm      = lane & 15;
    const int lq      = lane >> 4;
    const int n0      = w8 * 64 + wv * 16;   // this wave's 16 output rows

    const float* __restrict__ Wh = dir ? Whb : Whf;
    const float* __restrict__ h0 = dir ? h0b : h0f;
    _Float16* hg = hglob + (size_t)cluster * (2 * 16 * 512);
    int* ctr = bar + cluster * 32;

    // ---- one-time: load Wh slice into registers as f16 B-fragments ----
    // B-operand layout: B[k][n]: n = lane&15, k = (lane>>4)*8 + j
    half8 bfrag[16];
    {
        const float* wrow = Wh + (size_t)(n0 + lm) * H_SZ;
        #pragma unroll
        for (int kt = 0; kt < 16; kt++) {
            const float* p = wrow + kt*32 + lq*8;
            half8 v;
            #pragma unroll
            for (int j = 0; j < 8; j++) v[j] = (_Float16)p[j];
            bfrag[kt] = v;
        }
    }

    // ---- one-time: init h buffers (buffer0 = h0, buffer1 pads zeroed) ----
    {
        const int c  = tid >> 4;             // 0..15 (chain incl. padding)
        const int r0 = w8*64 + (tid & 15)*4; // 4 rows of this WG's slice
        #pragma unroll
        for (int j = 0; j < 4; j++) {
            float v = (c < 4) ? h0[(size_t)(b0 + c)*H_SZ + r0 + j] : 0.0f;
            hg[c*512 + r0 + j]           = (_Float16)v;
            hg[16*512 + c*512 + r0 + j]  = (_Float16)0.0f;
        }
    }
    __threadfence();
    __syncthreads();
    if (tid == 0) {
        __hip_atomic_fetch_add(ctr, 1, __ATOMIC_ACQ_REL, __HIP_MEMORY_SCOPE_AGENT);
        while (__hip_atomic_load(ctr, __ATOMIC_ACQUIRE, __HIP_MEMORY_SCOPE_AGENT) < 8) {}
    }
    __syncthreads();
    __threadfence();

    for (int s = 0; s < T_LEN; s++) {
        const int t = dir ? (T_LEN - 1 - s) : s;
        const _Float16* hread  = hg + (s & 1) * (16*512);
        _Float16*       hwrite = hg + ((s + 1) & 1) * (16*512);

        // prefetch xp for this step (only lanes lq==0 consume it)
        float xpv[4] = {0.f, 0.f, 0.f, 0.f};
        if (lq == 0) {
            const int r = n0 + lm;
            #pragma unroll
            for (int j = 0; j < 4; j++)
                xpv[j] = (float)xp[(((size_t)dir*T_LEN + t)*B_SZ + (b0 + j))*H_SZ + r];
        }

        // A-fragments: h for 16 "chains" (4 real + 12 zero pads)
        half8 af[16];
        #pragma unroll
        for (int kt = 0; kt < 16; kt++)
            af[kt] = *(const half8*)(hread + lm*512 + kt*32 + lq*8);

        float4v acc = {0.f, 0.f, 0.f, 0.f};
        #pragma unroll
        for (int kt = 0; kt < 16; kt++)
            acc = __builtin_amdgcn_mfma_f32_16x16x32_f16(af[kt], bfrag[kt], acc, 0, 0, 0);

        // chains 0..3 live in lanes 0..15 (lq==0), regs j=0..3; col = row index
        if (lq == 0) {
            const int r = n0 + lm;
            #pragma unroll
            for (int j = 0; j < 4; j++) {
                const int b = b0 + j;
                const float hv = tanhf(acc[j] + xpv[j]);
                out[((size_t)b*T_LEN + t)*1024 + dir*512 + r] = hv;
                hwrite[j*512 + r] = (_Float16)hv;
                if (s == T_LEN - 1)
                    out[(size_t)33554432 + dir*32768 + b*H_SZ + r] = hv;
            }
        }

        // per-cluster device-scope barrier (monotonic arrival counter)
        __threadfence();
        __syncthreads();
        if (tid == 0) {
            __hip_atomic_fetch_add(ctr, 1, __ATOMIC_ACQ_REL, __HIP_MEMORY_SCOPE_AGENT);
            const int target = 8 * (s + 2);
            while (__hip_atomic_load(ctr, __ATOMIC_ACQUIRE, __HIP_MEMORY_SCOPE_AGENT) < target) {}
        }
        __syncthreads();
        __threadfence();
    }
}

// ---------------------------------------------------------------------------
// ws layout (bytes):
//   [0,            67108864)  xp       : 2*512*64*512 f16
//   [67108864,     68157440)  hglob    : 32 clusters * 2 * 16 * 512 f16
//   [68157440,     68161536)  barriers : 32 * 32 ints
// ---------------------------------------------------------------------------
extern "C" void kernel_launch(void* const* d_in, const int* in_sizes, int n_in,
                              void* d_out, int out_size, void* d_ws, size_t ws_size,
                              hipStream_t stream) {
    const float* x   = (const float*)d_in[0];
    const float* h0f = (const float*)d_in[1];
    const float* h0b = (const float*)d_in[2];
    const float* Wxf = (const float*)d_in[3];
    const float* bxf = (const float*)d_in[4];
    const float* Whf = (const float*)d_in[5];
    const float* Wxb = (const float*)d_in[6];
    const float* bxb = (const float*)d_in[7];
    const float* Whb = (const float*)d_in[8];
    float* out = (float*)d_out;

    char* ws = (char*)d_ws;
    _Float16* xp    = (_Float16*)ws;
    _Float16* hglob = (_Float16*)(ws + 67108864);
    int*      ctr   = (int*)(ws + 68157440);

    hipMemsetAsync(ctr, 0, 32 * 32 * sizeof(int), stream);

    hipLaunchKernelGGL(xproj_kernel, dim3(8192), dim3(256), 0, stream,
                       x, Wxf, bxf, Wxb, bxb, xp);
    hipLaunchKernelGGL(rnn_kernel, dim3(256), dim3(256), 0, stream,
                       xp, Whf, Whb, h0f, h0b, out, hglob, ctr);
}

// Round 2
// 4970.336 us; speedup vs baseline: 4.4525x; 4.4525x over previous
//
#include <hip/hip_runtime.h>

#define T_LEN 512
#define B_SZ  64
#define I_SZ  512
#define H_SZ  512

using half8   = __attribute__((ext_vector_type(8))) _Float16;
using float4v = __attribute__((ext_vector_type(4))) float;

// ---------------------------------------------------------------------------
// Kernel 1: input projection GEMM (f16 MFMA, fp32 accumulate) — unchanged.
//   xp[dir][t][b][h] = sum_i x[b][t][i] * Wx[dir][h][i] + bx[dir][h]  (f16)
// ---------------------------------------------------------------------------
__global__ __launch_bounds__(256) void xproj_kernel(
    const float* __restrict__ x,
    const float* __restrict__ Wf, const float* __restrict__ bf,
    const float* __restrict__ Wb, const float* __restrict__ bb,
    _Float16* __restrict__ xp)
{
    __shared__ _Float16 Ash[64][72];
    __shared__ _Float16 Bsh[64][72];

    const int bid = blockIdx.x;
    const int dir = bid & 1;
    const int nt  = (bid >> 1) & 7;
    const int t   = bid >> 4;
    const float* __restrict__ W    = dir ? Wb : Wf;
    const float* __restrict__ bias = dir ? bb : bf;
    const int n0 = nt * 64;

    const int tid  = threadIdx.x;
    const int row  = tid >> 2;
    const int part = tid & 3;
    const int wv   = tid >> 6;
    const int lane = tid & 63;
    const int lm   = lane & 15;
    const int lq   = lane >> 4;

    float4v acc[4] = {{0,0,0,0},{0,0,0,0},{0,0,0,0},{0,0,0,0}};

    const float* ap = x + ((size_t)row * T_LEN + t) * I_SZ + part * 16;
    const float* bp = W + ((size_t)(n0 + row)) * I_SZ + part * 16;

    for (int k0 = 0; k0 < I_SZ; k0 += 64) {
        float areg[16], breg[16];
        #pragma unroll
        for (int i = 0; i < 16; i++) { areg[i] = ap[k0 + i]; breg[i] = bp[k0 + i]; }
        __syncthreads();
        #pragma unroll
        for (int i = 0; i < 16; i++) {
            Ash[row][part*16 + i] = (_Float16)areg[i];
            Bsh[row][part*16 + i] = (_Float16)breg[i];
        }
        __syncthreads();
        #pragma unroll
        for (int ks = 0; ks < 2; ks++) {
            half8 afr = *(const half8*)&Ash[16*wv + lm][ks*32 + lq*8];
            #pragma unroll
            for (int ns = 0; ns < 4; ns++) {
                half8 bfr = *(const half8*)&Bsh[ns*16 + lm][ks*32 + lq*8];
                acc[ns] = __builtin_amdgcn_mfma_f32_16x16x32_f16(afr, bfr, acc[ns], 0, 0, 0);
            }
        }
    }

    #pragma unroll
    for (int ns = 0; ns < 4; ns++) {
        const int n = n0 + ns*16 + lm;
        const float bv = bias[n];
        #pragma unroll
        for (int j = 0; j < 4; j++) {
            const int b = 16*wv + lq*4 + j;
            xp[(((size_t)dir*T_LEN + t)*B_SZ + b)*H_SZ + n] = (_Float16)(acc[ns][j] + bv);
        }
    }
}

// ---------------------------------------------------------------------------
// Kernel 2: recurrence, fence-free tagged exchange through L3.
// 64 WGs x 256 thr. cluster = blk>>3 (8 clusters: dir = c>>2, 16 chains each),
// w8 = blk&7 picks the 64-dim slice of Wh (register-resident f16 B-frags).
// Exchange buffer hx[cluster][parity][ch*512+dim]: dword = (tag<<16)|f16(h),
// tag = step+1. Relaxed AGENT-scope atomics => sc1 => coherent via L3;
// NO fences, NO barrier counter. Poison 0xAAAA never matches tags 1..511.
// Overwrite safety: a WG stores tag s+2 only after staging all of tag s+1,
// which requires every WG (incl. the slowest) to have stored tag s+1, which
// requires it to have fully read tag s. Two parities therefore suffice.
// ---------------------------------------------------------------------------
__global__ __launch_bounds__(256) void rnn_kernel(
    const _Float16* __restrict__ xp,     // [2][T][B][H] f16
    const float* __restrict__ Whf, const float* __restrict__ Whb,
    const float* __restrict__ h0f, const float* __restrict__ h0b,
    float* __restrict__ out,             // y[B][T][2H] ++ hTf[B][H] ++ hTb[B][H]
    unsigned int* __restrict__ hx)       // [8][2][16*512] dwords
{
    const int blk     = blockIdx.x;
    const int cluster = blk >> 3;        // 0..7
    const int w8      = blk & 7;         // 0..7 : dim slice
    const int dir     = cluster >> 2;
    const int b0      = (cluster & 3) * 16;
    const int tid     = threadIdx.x;
    const int wv      = tid >> 6;
    const int lane    = tid & 63;
    const int lm      = lane & 15;
    const int lq      = lane >> 4;
    const int n0      = w8 * 64 + wv * 16;   // this wave's 16 output dims

    const float* __restrict__ Wh = dir ? Whb : Whf;
    const float* __restrict__ h0 = dir ? h0b : h0f;
    unsigned int* buf = hx + (size_t)cluster * (2 * 16 * 512);

    __shared__ _Float16 hl[16 * 520];    // h staged: [ch][dim], row stride 520

    // ---- one-time: Wh slice -> f16 B-fragments (B[k][n]: n=lm, k=lq*8+j) ----
    half8 bfrag[16];
    {
        const float* wrow = Wh + (size_t)(n0 + lm) * H_SZ;
        #pragma unroll
        for (int kt = 0; kt < 16; kt++) {
            const float* p = wrow + kt*32 + lq*8;
            half8 v;
            #pragma unroll
            for (int j = 0; j < 8; j++) v[j] = (_Float16)p[j];
            bfrag[kt] = v;
        }
    }

    // ---- stage h0 into LDS (coalesced fp32 loads) ----
    #pragma unroll 4
    for (int j = 0; j < 32; j++) {
        const int idx = j*256 + tid;
        const int ch = idx >> 9, d = idx & 511;
        hl[ch*520 + d] = (_Float16)h0[(size_t)(b0 + ch)*H_SZ + d];
    }
    __syncthreads();

    for (int s = 0; s < T_LEN; s++) {
        const int t = dir ? (T_LEN - 1 - s) : s;

        // xp for this step (independent of exchange — issue early)
        float xpv[4];
        #pragma unroll
        for (int j = 0; j < 4; j++)
            xpv[j] = (float)xp[(((size_t)dir*T_LEN + t)*B_SZ + (b0 + lq*4 + j))*H_SZ + n0 + lm];

        if (s > 0) {
            __syncthreads();   // protect previous step's af reads before restaging
            const unsigned int want = (unsigned int)s;
            const unsigned int* src = buf + (s & 1) * (16*512);
            unsigned int v[32];
            #pragma unroll
            for (int j = 0; j < 32; j++)
                v[j] = __hip_atomic_load(src + j*256 + tid, __ATOMIC_RELAXED, __HIP_MEMORY_SCOPE_AGENT);
            #pragma unroll
            for (int j = 0; j < 32; j++) {
                while ((v[j] >> 16) != want)
                    v[j] = __hip_atomic_load(src + j*256 + tid, __ATOMIC_RELAXED, __HIP_MEMORY_SCOPE_AGENT);
                const int idx = j*256 + tid;
                unsigned short hb = (unsigned short)(v[j] & 0xFFFFu);
                hl[(idx >> 9)*520 + (idx & 511)] = __builtin_bit_cast(_Float16, hb);
            }
            __syncthreads();
        }

        // A-fragments from LDS: A[m=ch=lm][k=dim], 16 k-tiles
        half8 af[16];
        #pragma unroll
        for (int kt = 0; kt < 16; kt++)
            af[kt] = *(const half8*)&hl[lm*520 + kt*32 + lq*8];

        float4v acc = {0.f, 0.f, 0.f, 0.f};
        #pragma unroll
        for (int kt = 0; kt < 16; kt++)
            acc = __builtin_amdgcn_mfma_f32_16x16x32_f16(af[kt], bfrag[kt], acc, 0, 0, 0);

        // C/D: col = dim n0+lm, row = chain lq*4+j
        #pragma unroll
        for (int j = 0; j < 4; j++) {
            const int c = lq*4 + j;
            const int b = b0 + c;
            const int r = n0 + lm;
            const float hv = tanhf(acc[j] + xpv[j]);
            __builtin_nontemporal_store(hv, &out[((size_t)b*T_LEN + t)*1024 + dir*512 + r]);
            if (s == T_LEN - 1) {
                __builtin_nontemporal_store(hv, &out[(size_t)33554432 + dir*32768 + (size_t)b*H_SZ + r]);
            } else {
                unsigned short hb = __builtin_bit_cast(unsigned short, (_Float16)hv);
                unsigned int word = ((unsigned int)(s + 1) << 16) | (unsigned int)hb;
                __hip_atomic_store(buf + ((s + 1) & 1)*(16*512) + c*512 + r, word,
                                   __ATOMIC_RELAXED, __HIP_MEMORY_SCOPE_AGENT);
            }
        }
    }
}

// ---------------------------------------------------------------------------
// ws layout (bytes):
//   [0,        67108864)  xp : 2*512*64*512 f16
//   [67108864, 67633152)  hx : 8 clusters * 2 * 8192 dwords
// No init needed: 0xAA poison gives tag 0xAAAA which never matches 1..511.
// ---------------------------------------------------------------------------
extern "C" void kernel_launch(void* const* d_in, const int* in_sizes, int n_in,
                              void* d_out, int out_size, void* d_ws, size_t ws_size,
                              hipStream_t stream) {
    const float* x   = (const float*)d_in[0];
    const float* h0f = (const float*)d_in[1];
    const float* h0b = (const float*)d_in[2];
    const float* Wxf = (const float*)d_in[3];
    const float* bxf = (const float*)d_in[4];
    const float* Whf = (const float*)d_in[5];
    const float* Wxb = (const float*)d_in[6];
    const float* bxb = (const float*)d_in[7];
    const float* Whb = (const float*)d_in[8];
    float* out = (float*)d_out;

    char* ws = (char*)d_ws;
    _Float16*     xpb = (_Float16*)ws;
    unsigned int* hx  = (unsigned int*)(ws + 67108864);

    hipLaunchKernelGGL(xproj_kernel, dim3(8192), dim3(256), 0, stream,
                       x, Wxf, bxf, Wxb, bxb, xpb);
    hipLaunchKernelGGL(rnn_kernel, dim3(64), dim3(256), 0, stream,
                       xpb, Whf, Whb, h0f, h0b, out, hx);
}

// Round 4
// 1829.210 us; speedup vs baseline: 12.0985x; 2.7172x over previous
//
#include <hip/hip_runtime.h>

#define T_LEN 512
#define B_SZ  64
#define I_SZ  512
#define H_SZ  512

using half8   = __attribute__((ext_vector_type(8))) _Float16;
using float4v = __attribute__((ext_vector_type(4))) float;

__device__ __forceinline__ float fast_tanh(float x) {
    // 1 - 2/(e^{2x}+1): monotone, saturates to +/-1, no NaN (inf -> 1, 0 -> -1)
    float e = __expf(2.0f * x);
    return 1.0f - 2.0f * __builtin_amdgcn_rcpf(e + 1.0f);
}

// ---------------------------------------------------------------------------
// Kernel 1: input projection GEMM (f16 MFMA, fp32 accumulate) — unchanged.
// ---------------------------------------------------------------------------
__global__ __launch_bounds__(256) void xproj_kernel(
    const float* __restrict__ x,
    const float* __restrict__ Wf, const float* __restrict__ bf,
    const float* __restrict__ Wb, const float* __restrict__ bb,
    _Float16* __restrict__ xp)
{
    __shared__ _Float16 Ash[64][72];
    __shared__ _Float16 Bsh[64][72];

    const int bid = blockIdx.x;
    const int dir = bid & 1;
    const int nt  = (bid >> 1) & 7;
    const int t   = bid >> 4;
    const float* __restrict__ W    = dir ? Wb : Wf;
    const float* __restrict__ bias = dir ? bb : bf;
    const int n0 = nt * 64;

    const int tid  = threadIdx.x;
    const int row  = tid >> 2;
    const int part = tid & 3;
    const int wv   = tid >> 6;
    const int lane = tid & 63;
    const int lm   = lane & 15;
    const int lq   = lane >> 4;

    float4v acc[4] = {{0,0,0,0},{0,0,0,0},{0,0,0,0},{0,0,0,0}};

    const float* ap = x + ((size_t)row * T_LEN + t) * I_SZ + part * 16;
    const float* bp = W + ((size_t)(n0 + row)) * I_SZ + part * 16;

    for (int k0 = 0; k0 < I_SZ; k0 += 64) {
        float areg[16], breg[16];
        #pragma unroll
        for (int i = 0; i < 16; i++) { areg[i] = ap[k0 + i]; breg[i] = bp[k0 + i]; }
        __syncthreads();
        #pragma unroll
        for (int i = 0; i < 16; i++) {
            Ash[row][part*16 + i] = (_Float16)areg[i];
            Bsh[row][part*16 + i] = (_Float16)breg[i];
        }
        __syncthreads();
        #pragma unroll
        for (int ks = 0; ks < 2; ks++) {
            half8 afr = *(const half8*)&Ash[16*wv + lm][ks*32 + lq*8];
            #pragma unroll
            for (int ns = 0; ns < 4; ns++) {
                half8 bfr = *(const half8*)&Bsh[ns*16 + lm][ks*32 + lq*8];
                acc[ns] = __builtin_amdgcn_mfma_f32_16x16x32_f16(afr, bfr, acc[ns], 0, 0, 0);
            }
        }
    }

    #pragma unroll
    for (int ns = 0; ns < 4; ns++) {
        const int n = n0 + ns*16 + lm;
        const float bv = bias[n];
        #pragma unroll
        for (int j = 0; j < 4; j++) {
            const int b = 16*wv + lq*4 + j;
            xp[(((size_t)dir*T_LEN + t)*B_SZ + b)*H_SZ + n] = (_Float16)(acc[ns][j] + bv);
        }
    }
}

// ---------------------------------------------------------------------------
// Kernel 2: recurrence with flag-released bulk exchange through L3.
// 32 WGs x 256 thr. cluster = blk&7 (dir = c>>2, 16 chains), w4 = blk>>3
// picks a 128-dim slice of Wh (32 half8 B-frags in VGPRs per wave).
// Exchange: fp32 slab in MFMA-A-fragment order, per-cluster ping-pong.
//   q(ch,k) = (k>>3)*128 + ch*8 + (k&7)   (fp32 elements)
// Writer: 8 relaxed-sc1 dword stores -> s_waitcnt(0) + __syncthreads (release)
//   -> tid0 stores flag[w4] = s+1 (relaxed sc1).
// Reader: spin on 4 flags (relaxed sc1, 4 dwords only), compiler mem-clobber,
//   then 16 b64 relaxed-sc1 loads (one L3 round trip), pack f16 -> LDS.
// Ping-pong safety: flag s+1 from WG W implies W finished READING parity
// (s-1)&1, so overwriting that parity at step s+1 is safe (induction).
// ---------------------------------------------------------------------------
__global__ __launch_bounds__(256, 1) void rnn_kernel(
    const _Float16* __restrict__ xp,     // [2][T][B][H] f16
    const float* __restrict__ Whf, const float* __restrict__ Whb,
    const float* __restrict__ h0f, const float* __restrict__ h0b,
    float* __restrict__ out,             // y[B][T][2H] ++ hTf ++ hTb
    float* __restrict__ slab,            // [8][2][8192] f32 frag-ordered
    unsigned int* __restrict__ flags)    // [8][4] dwords at 16-dword spacing
{
    const int blk     = blockIdx.x;
    const int cluster = blk & 7;
    const int w4      = blk >> 3;        // 0..3 : 128-dim slice
    const int dir     = cluster >> 2;
    const int b0      = (cluster & 3) * 16;
    const int tid     = threadIdx.x;
    const int wv      = tid >> 6;
    const int lane    = tid & 63;
    const int lm      = lane & 15;
    const int lq      = lane >> 4;
    const int nbase   = w4*128 + wv*32;  // wave's 32 dims (2 n-tiles)

    const float* __restrict__ Wh = dir ? Whb : Whf;
    const float* __restrict__ h0 = dir ? h0b : h0f;
    float* slab0 = slab + (size_t)cluster * (2 * 8192);
    unsigned int* fl = flags + cluster * 64;

    __shared__ _Float16 hl[8192];        // h in A-fragment order (16 KB)

    // ---- one-time: Wh slice -> f16 B-fragments (B[k][n]: n=lm, k=lq*8+j) ----
    half8 bfrag[2][16];
    #pragma unroll
    for (int nt = 0; nt < 2; nt++) {
        const float* wrow = Wh + (size_t)(nbase + nt*16 + lm) * H_SZ;
        #pragma unroll
        for (int kt = 0; kt < 16; kt++) {
            const float* p = wrow + kt*32 + lq*8;
            half8 v;
            #pragma unroll
            for (int j = 0; j < 8; j++) v[j] = (_Float16)p[j];
            bfrag[nt][kt] = v;
        }
    }

    // ---- stage h0 into LDS in fragment order ----
    #pragma unroll 4
    for (int j = 0; j < 32; j++) {
        const int q  = j*256 + tid;
        const int ch = (q >> 3) & 15;
        const int k  = (q >> 7) * 8 + (q & 7);
        hl[q] = (_Float16)h0[(size_t)(b0 + ch)*H_SZ + k];
    }
    __syncthreads();

    for (int s = 0; s < T_LEN; s++) {
        const int t = dir ? (T_LEN - 1 - s) : s;

        // xp for this step — issued before the poll, consumed after MFMA
        float xpv[2][4];
        #pragma unroll
        for (int nt = 0; nt < 2; nt++)
            #pragma unroll
            for (int j = 0; j < 4; j++)
                xpv[nt][j] = (float)xp[(((size_t)dir*T_LEN + t)*B_SZ + (b0 + lq*4 + j))*H_SZ
                                       + nbase + nt*16 + lm];

        if (s > 0) {
            const unsigned int want = (unsigned int)s;
            unsigned int f0, f1, f2, f3;
            do {
                f0 = __hip_atomic_load(fl +  0, __ATOMIC_RELAXED, __HIP_MEMORY_SCOPE_AGENT);
                f1 = __hip_atomic_load(fl + 16, __ATOMIC_RELAXED, __HIP_MEMORY_SCOPE_AGENT);
                f2 = __hip_atomic_load(fl + 32, __ATOMIC_RELAXED, __HIP_MEMORY_SCOPE_AGENT);
                f3 = __hip_atomic_load(fl + 48, __ATOMIC_RELAXED, __HIP_MEMORY_SCOPE_AGENT);
            } while (f0 < want || f1 < want || f2 < want || f3 < want);
            asm volatile("" ::: "memory");   // no reordering of slab loads above polls

            const unsigned long long* src =
                (const unsigned long long*)(slab0 + (s & 1) * 8192);
            unsigned long long v[16];
            #pragma unroll
            for (int j = 0; j < 16; j++)
                v[j] = __hip_atomic_load(src + j*256 + tid, __ATOMIC_RELAXED,
                                         __HIP_MEMORY_SCOPE_AGENT);
            #pragma unroll
            for (int j = 0; j < 16; j++) {
                const float lo = __builtin_bit_cast(float, (unsigned int)(v[j] & 0xFFFFFFFFu));
                const float hi = __builtin_bit_cast(float, (unsigned int)(v[j] >> 32));
                auto h2 = __builtin_amdgcn_cvt_pkrtz(lo, hi);   // __fp16 ext_vector(2)
                ((unsigned int*)hl)[j*256 + tid] = __builtin_bit_cast(unsigned int, h2);
            }
            __syncthreads();
        }

        // A-fragments: contiguous per quarter-wave -> conflict-free b128
        half8 af[16];
        #pragma unroll
        for (int kt = 0; kt < 16; kt++)
            af[kt] = *(const half8*)&hl[kt*512 + lq*128 + lm*8];

        float4v acc[2] = {{0,0,0,0},{0,0,0,0}};
        #pragma unroll
        for (int kt = 0; kt < 16; kt++) {
            acc[0] = __builtin_amdgcn_mfma_f32_16x16x32_f16(af[kt], bfrag[0][kt], acc[0], 0, 0, 0);
            acc[1] = __builtin_amdgcn_mfma_f32_16x16x32_f16(af[kt], bfrag[1][kt], acc[1], 0, 0, 0);
        }

        float* dst = slab0 + ((s + 1) & 1) * 8192;
        #pragma unroll
        for (int nt = 0; nt < 2; nt++) {
            #pragma unroll
            for (int j = 0; j < 4; j++) {
                const int ch = lq*4 + j;
                const int d  = nbase + nt*16 + lm;
                const float hv = fast_tanh(acc[nt][j] + xpv[nt][j]);
                __builtin_nontemporal_store(hv,
                    &out[((size_t)(b0 + ch)*T_LEN + t)*1024 + dir*512 + d]);
                if (s == T_LEN - 1) {
                    __builtin_nontemporal_store(hv,
                        &out[(size_t)33554432 + dir*32768 + (size_t)(b0 + ch)*H_SZ + d]);
                } else {
                    const int q = (nbase + nt*16)*16 + (lm >> 3)*128 + ch*8 + (lm & 7);
                    __hip_atomic_store(dst + q, hv, __ATOMIC_RELAXED, __HIP_MEMORY_SCOPE_AGENT);
                }
            }
        }

        __builtin_amdgcn_s_waitcnt(0);   // per-wave: slab stores drained to L3
        __syncthreads();                  // all waves drained -> release point
        if (s < T_LEN - 1 && tid == 0)
            __hip_atomic_store(fl + w4*16, (unsigned int)(s + 1),
                               __ATOMIC_RELAXED, __HIP_MEMORY_SCOPE_AGENT);
    }
}

// ---------------------------------------------------------------------------
// ws layout (bytes):
//   [0,        67108864)  xp    : 2*512*64*512 f16
//   [67108864, 67633152)  slab  : 8 clusters * 2 * 8192 f32
//   [67633152, 67635200)  flags : 8 clusters * 64 dwords (zeroed each launch)
// ---------------------------------------------------------------------------
extern "C" void kernel_launch(void* const* d_in, const int* in_sizes, int n_in,
                              void* d_out, int out_size, void* d_ws, size_t ws_size,
                              hipStream_t stream) {
    const float* x   = (const float*)d_in[0];
    const float* h0f = (const float*)d_in[1];
    const float* h0b = (const float*)d_in[2];
    const float* Wxf = (const float*)d_in[3];
    const float* bxf = (const float*)d_in[4];
    const float* Whf = (const float*)d_in[5];
    const float* Wxb = (const float*)d_in[6];
    const float* bxb = (const float*)d_in[7];
    const float* Whb = (const float*)d_in[8];
    float* out = (float*)d_out;

    char* ws = (char*)d_ws;
    _Float16*     xpb  = (_Float16*)ws;
    float*        slab = (float*)(ws + 67108864);
    unsigned int* flg  = (unsigned int*)(ws + 67633152);

    (void)hipMemsetAsync(flg, 0, 8 * 64 * sizeof(unsigned int), stream);

    hipLaunchKernelGGL(xproj_kernel, dim3(8192), dim3(256), 0, stream,
                       x, Wxf, bxf, Wxb, bxb, xpb);
    hipLaunchKernelGGL(rnn_kernel, dim3(32), dim3(256), 0, stream,
                       xpb, Whf, Whb, h0f, h0b, out, slab, flg);
}